// Round 4
// baseline (31.934 us; speedup 1.0000x reference)
//
#include <hip/hip_runtime.h>
#include <hip/hip_bf16.h>

#define CIN 32
#define HW 64
#define KK 64
#define NLEAF 8
#define PADDING 2
#define TW 12                 // 12x12 staged window per 8x8 output tile
#define TSZ (CIN * TW * TW)   // 4608 floats = 18432 B

__device__ __constant__ float d_C[16][4] = {
    {0, 0, 0, 0},  {0, 0, 0, 1},  {0, 1, 0, -1}, {0, 1, 0, 0},
    {0, 0, 1, -1}, {0, 0, 1, 0},  {0, 1, 1, -2}, {0, 1, 1, -1},
    {1, -1, -1, 1},{1, -1, -1, 2},{1, 0, -1, 0}, {1, 0, -1, 1},
    {1, -1, 0, 0}, {1, -1, 0, 1}, {1, 0, 0, -1}, {1, 0, 0, 0}
};

// blocks 0..3: coefA[k*60 + node*4 + c]  (softmax(w) . C)
// block 4, threads 0..63: loffA[k*16 + n] = c*144 + dh*12 + dw  (LDS-tile offsets)
__global__ __launch_bounds__(256) void prep_kernel(
    const int* __restrict__ idx_h, const int* __restrict__ idx_w, const int* __restrict__ idx_c,
    const float* __restrict__ w0, const float* __restrict__ w1,
    const float* __restrict__ w2, const float* __restrict__ w3,
    float* __restrict__ coefA, int* __restrict__ loffA)
{
    if (blockIdx.x == 4) {
        int k = threadIdx.x;
        if (k < KK) {
            #pragma unroll
            for (int n = 0; n < 16; ++n) {
                int s = n >> 3, leaf = n & 7;
                int o = s * (KK * NLEAF) + k * NLEAF + leaf;
                loffA[k * 16 + n] = idx_c[o] * (TW * TW) + idx_h[o] * TW + idx_w[o];
            }
        }
        return;
    }
    int t = blockIdx.x * blockDim.x + threadIdx.x;
    if (t >= KK * 15) return;
    int k = t / 15, node = t % 15;
    const float* wp; int n;
    if (node < 8)       { wp = w0; n = node; }
    else if (node < 12) { wp = w1; n = node - 8; }
    else if (node < 14) { wp = w2; n = node - 12; }
    else                { wp = w3; n = 0; }
    const float* l = wp + (n * KK + k) * 16;
    float m = l[0];
    #pragma unroll
    for (int g = 1; g < 16; ++g) m = fmaxf(m, l[g]);
    float p[16], s = 0.f;
    #pragma unroll
    for (int g = 0; g < 16; ++g) { p[g] = expf(l[g] - m); s += p[g]; }
    float inv = 1.f / s;
    float c0 = 0, c1 = 0, c2 = 0, c3 = 0;
    #pragma unroll
    for (int g = 0; g < 16; ++g) {
        float w = p[g] * inv;
        c0 = fmaf(w, d_C[g][0], c0);
        c1 = fmaf(w, d_C[g][1], c1);
        c2 = fmaf(w, d_C[g][2], c2);
        c3 = fmaf(w, d_C[g][3], c3);
    }
    float* o = coefA + (k * 60 + node * 4);
    o[0] = c0; o[1] = c1; o[2] = c2; o[3] = c3;
}

__device__ __forceinline__ float gate(const float* c, float a, float b) {
    return fmaf(b, fmaf(a, c[3], c[2]), fmaf(a, c[1], c[0]));
}

// One block per (b, 8x8 tile); 4 waves x 16 k; lane = pixel.
__global__ __launch_bounds__(256) void logic_conv_kernel(
    const float* __restrict__ x, const int* __restrict__ loffA,
    const float* __restrict__ coefA, float* __restrict__ out)
{
    __shared__ float xt[TSZ];

    int tid  = threadIdx.x;
    int b    = blockIdx.x >> 6;
    int tile = blockIdx.x & 63;
    int r0 = (tile >> 3) << 3, c0 = (tile & 7) << 3;

    const float* xb = x + (size_t)b * (CIN * HW * HW);

    // Stage 32 x 12 x 12 padded window (zero-fill outside the image).
    #pragma unroll
    for (int i = 0; i < 18; ++i) {
        int e  = tid + i * 256;
        int c  = e / 144;
        int r  = e - c * 144;
        int rr = r / TW;
        int cc = r - rr * TW;
        int ih = r0 + rr - PADDING, iw = c0 + cc - PADDING;
        float v = 0.f;
        if ((unsigned)ih < HW && (unsigned)iw < HW)
            v = xb[(c * HW + ih) * HW + iw];
        xt[e] = v;
    }
    __syncthreads();

    int lane = tid & 63, wave = tid >> 6;
    int tr = lane >> 3, tc = lane & 7;
    int pxoff = tr * TW + tc;                    // gather offset within tile
    int pxout = (r0 + tr) * HW + (c0 + tc);      // per-lane output offset
    float* outb = out + ((size_t)b << 18);       // b * 64 * 4096

    #pragma unroll 1
    for (int i = 0; i < 16; ++i) {
        int k = __builtin_amdgcn_readfirstlane((wave << 4) + i);
        const int*   L = loffA + (k << 4);
        const float* C = coefA + k * 60;

        float g[16];
        #pragma unroll
        for (int n = 0; n < 16; ++n)
            g[n] = xt[L[n] + pxoff];

        float v[8];
        #pragma unroll
        for (int n = 0; n < 8; ++n)
            v[n] = gate(C + 4 * n, g[n], g[8 + n]);
        float u[4];
        #pragma unroll
        for (int n = 0; n < 4; ++n)
            u[n] = gate(C + 32 + 4 * n, v[2 * n], v[2 * n + 1]);
        float t0 = gate(C + 48, u[0], u[1]);
        float t1 = gate(C + 52, u[2], u[3]);
        outb[((size_t)k << 12) + pxout] = gate(C + 56, t0, t1);
    }
}

extern "C" void kernel_launch(void* const* d_in, const int* in_sizes, int n_in,
                              void* d_out, int out_size, void* d_ws, size_t ws_size,
                              hipStream_t stream) {
    const float* x     = (const float*)d_in[0];
    const int*   idx_h = (const int*)d_in[1];
    const int*   idx_w = (const int*)d_in[2];
    const int*   idx_c = (const int*)d_in[3];
    const float* w0    = (const float*)d_in[4];
    const float* w1    = (const float*)d_in[5];
    const float* w2    = (const float*)d_in[6];
    const float* w3    = (const float*)d_in[7];
    float* out   = (float*)d_out;

    float* coefA = (float*)d_ws;                      // 15,360 B
    int*   loffA = (int*)((char*)d_ws + 16384);       // 4,096 B

    hipLaunchKernelGGL(prep_kernel, dim3(5), dim3(256), 0, stream,
                       idx_h, idx_w, idx_c, w0, w1, w2, w3, coefA, loffA);
    // 16 b * 64 tiles = 1024 blocks
    hipLaunchKernelGGL(logic_conv_kernel, dim3(1024), dim3(256), 0, stream,
                       x, loffA, coefA, out);
}

// Round 5
// 29.115 us; speedup vs baseline: 1.0968x; 1.0968x over previous
//
#include <hip/hip_runtime.h>
#include <hip/hip_bf16.h>

#define CIN 32
#define HW 64
#define KK 64
#define NLEAF 8
#define PADDING 2
#define TW 12                   // 12x12 staged window per 8x8 output tile
#define WPOS (CIN * TW * TW)    // 4608 positions; float2 each -> 36864 B LDS

typedef float f32x2 __attribute__((ext_vector_type(2)));

__device__ __constant__ float d_C[16][4] = {
    {0, 0, 0, 0},  {0, 0, 0, 1},  {0, 1, 0, -1}, {0, 1, 0, 0},
    {0, 0, 1, -1}, {0, 0, 1, 0},  {0, 1, 1, -2}, {0, 1, 1, -1},
    {1, -1, -1, 1},{1, -1, -1, 2},{1, 0, -1, 0}, {1, 0, -1, 1},
    {1, -1, 0, 0}, {1, -1, 0, 1}, {1, 0, 0, -1}, {1, 0, 0, 0}
};

// blocks 0..3: coefA[k*60 + node*4 + c]; block 4: loffA[k*16+n] = BYTE offset
// of leaf (c,dh,dw) in the float2-interleaved 32x12x12 window.
__global__ __launch_bounds__(256) void prep_kernel(
    const int* __restrict__ idx_h, const int* __restrict__ idx_w, const int* __restrict__ idx_c,
    const float* __restrict__ w0, const float* __restrict__ w1,
    const float* __restrict__ w2, const float* __restrict__ w3,
    float* __restrict__ coefA, int* __restrict__ loffA)
{
    if (blockIdx.x == 4) {
        int k = threadIdx.x;
        if (k < KK) {
            #pragma unroll
            for (int n = 0; n < 16; ++n) {
                int s = n >> 3, leaf = n & 7;
                int o = s * (KK * NLEAF) + k * NLEAF + leaf;
                loffA[k * 16 + n] = (idx_c[o] * (TW * TW) + idx_h[o] * TW + idx_w[o]) * 8;
            }
        }
        return;
    }
    int t = blockIdx.x * blockDim.x + threadIdx.x;
    if (t >= KK * 15) return;
    int k = t / 15, node = t % 15;
    const float* wp; int n;
    if (node < 8)       { wp = w0; n = node; }
    else if (node < 12) { wp = w1; n = node - 8; }
    else if (node < 14) { wp = w2; n = node - 12; }
    else                { wp = w3; n = 0; }
    const float* l = wp + (n * KK + k) * 16;
    float m = l[0];
    #pragma unroll
    for (int g = 1; g < 16; ++g) m = fmaxf(m, l[g]);
    float p[16], s = 0.f;
    #pragma unroll
    for (int g = 0; g < 16; ++g) { p[g] = expf(l[g] - m); s += p[g]; }
    float inv = 1.f / s;
    float c0 = 0, c1 = 0, c2 = 0, c3 = 0;
    #pragma unroll
    for (int g = 0; g < 16; ++g) {
        float w = p[g] * inv;
        c0 = fmaf(w, d_C[g][0], c0);
        c1 = fmaf(w, d_C[g][1], c1);
        c2 = fmaf(w, d_C[g][2], c2);
        c3 = fmaf(w, d_C[g][3], c3);
    }
    float* o = coefA + (k * 60 + node * 4);
    o[0] = c0; o[1] = c1; o[2] = c2; o[3] = c3;
}

__device__ __forceinline__ f32x2 bc(float s) { return (f32x2){s, s}; }
__device__ __forceinline__ f32x2 gate2(const float* c, f32x2 a, f32x2 b) {
    return __builtin_elementwise_fma(b,
               __builtin_elementwise_fma(a, bc(c[3]), bc(c[2])),
               __builtin_elementwise_fma(a, bc(c[1]), bc(c[0])));
}

// One block per (batch-pair, 8x8 tile): 8*64 = 512 blocks; 4 waves x 16 k;
// lane = pixel; each lane computes 2 batch images via float2-interleaved LDS.
__global__ __launch_bounds__(256) void logic_conv_kernel(
    const float* __restrict__ x, const int* __restrict__ loffA,
    const float* __restrict__ coefA, float* __restrict__ out)
{
    __shared__ f32x2 xt[WPOS];

    int tid  = threadIdx.x;
    int bp   = blockIdx.x >> 6;
    int tile = blockIdx.x & 63;
    int r0 = (tile >> 3) << 3, c0 = (tile & 7) << 3;

    const float* xb0 = x + (size_t)(2 * bp) * (CIN * HW * HW);
    const float* xb1 = xb0 + (CIN * HW * HW);

    // Stage interleaved padded windows for both images.
    #pragma unroll
    for (int i = 0; i < 18; ++i) {
        int e  = tid + i * 256;
        int c  = e / (TW * TW);
        int r  = e - c * (TW * TW);
        int rr = r / TW;
        int cc = r - rr * TW;
        int ih = r0 + rr - PADDING, iw = c0 + cc - PADDING;
        f32x2 v = {0.f, 0.f};
        if ((unsigned)ih < HW && (unsigned)iw < HW) {
            int go = (c * HW + ih) * HW + iw;
            v.x = xb0[go];
            v.y = xb1[go];
        }
        xt[e] = v;
    }
    __syncthreads();

    int lane = tid & 63, wave = tid >> 6;
    int tr = lane >> 3, tc = lane & 7;
    int pxb   = (tr * TW + tc) * 8;            // per-lane LDS byte offset
    int pxout = (r0 + tr) * HW + (c0 + tc);    // per-lane output element offset
    float* outB0 = out + ((size_t)(2 * bp) << 18);       // b * 64 * 4096
    float* outB1 = outB0 + (1 << 18);
    const char* xtb = (const char*)xt;

    #pragma unroll 1
    for (int i = 0; i < 16; ++i) {
        int k = __builtin_amdgcn_readfirstlane((wave << 4) + i);
        const int*   L = loffA + (k << 4);
        const float* C = coefA + k * 60;

        f32x2 g[16];
        #pragma unroll
        for (int n = 0; n < 16; ++n)
            g[n] = *(const f32x2*)(xtb + (L[n] + pxb));

        f32x2 v[8];
        #pragma unroll
        for (int n = 0; n < 8; ++n)
            v[n] = gate2(C + 4 * n, g[n], g[8 + n]);
        f32x2 u[4];
        #pragma unroll
        for (int n = 0; n < 4; ++n)
            u[n] = gate2(C + 32 + 4 * n, v[2 * n], v[2 * n + 1]);
        f32x2 t0 = gate2(C + 48, u[0], u[1]);
        f32x2 t1 = gate2(C + 52, u[2], u[3]);
        f32x2 r  = gate2(C + 56, t0, t1);

        int ko = (k << 12) + pxout;
        outB0[ko] = r.x;
        outB1[ko] = r.y;
    }
}

extern "C" void kernel_launch(void* const* d_in, const int* in_sizes, int n_in,
                              void* d_out, int out_size, void* d_ws, size_t ws_size,
                              hipStream_t stream) {
    const float* x     = (const float*)d_in[0];
    const int*   idx_h = (const int*)d_in[1];
    const int*   idx_w = (const int*)d_in[2];
    const int*   idx_c = (const int*)d_in[3];
    const float* w0    = (const float*)d_in[4];
    const float* w1    = (const float*)d_in[5];
    const float* w2    = (const float*)d_in[6];
    const float* w3    = (const float*)d_in[7];
    float* out   = (float*)d_out;

    float* coefA = (float*)d_ws;                      // 15,360 B
    int*   loffA = (int*)((char*)d_ws + 16384);       // 4,096 B

    hipLaunchKernelGGL(prep_kernel, dim3(5), dim3(256), 0, stream,
                       idx_h, idx_w, idx_c, w0, w1, w2, w3, coefA, loffA);
    // 8 batch-pairs * 64 tiles = 512 blocks
    hipLaunchKernelGGL(logic_conv_kernel, dim3(512), dim3(256), 0, stream,
                       x, loffA, coefA, out);
}

// Round 6
// 26.963 us; speedup vs baseline: 1.1844x; 1.0798x over previous
//
#include <hip/hip_runtime.h>
#include <hip/hip_bf16.h>

#define CIN 32
#define HW 64
#define KK 64
#define NLEAF 8
#define PADDING 2
#define TH 4                    // tile rows
#define TCW 16                  // tile cols
#define WR 8                    // window rows = TH + 4
#define WC 20                   // window cols = TCW + 4
#define WPOS (CIN * WR * WC)    // 5120 positions; f32x2 each -> 40960 B LDS

typedef float f32x2 __attribute__((ext_vector_type(2)));

__device__ __constant__ float d_C[16][4] = {
    {0, 0, 0, 0},  {0, 0, 0, 1},  {0, 1, 0, -1}, {0, 1, 0, 0},
    {0, 0, 1, -1}, {0, 0, 1, 0},  {0, 1, 1, -2}, {0, 1, 1, -1},
    {1, -1, -1, 1},{1, -1, -1, 2},{1, 0, -1, 0}, {1, 0, -1, 1},
    {1, -1, 0, 0}, {1, -1, 0, 1}, {1, 0, 0, -1}, {1, 0, 0, 0}
};

// blocks 0..3: coefA[k*60 + node*4 + c]; block 4: loffA[k*16+n] = BYTE offset
// of leaf (c,dh,dw) in the f32x2-interleaved 32 x 8 x 20 window.
__global__ __launch_bounds__(256) void prep_kernel(
    const int* __restrict__ idx_h, const int* __restrict__ idx_w, const int* __restrict__ idx_c,
    const float* __restrict__ w0, const float* __restrict__ w1,
    const float* __restrict__ w2, const float* __restrict__ w3,
    float* __restrict__ coefA, int* __restrict__ loffA)
{
    if (blockIdx.x == 4) {
        int k = threadIdx.x;
        if (k < KK) {
            #pragma unroll
            for (int n = 0; n < 16; ++n) {
                int s = n >> 3, leaf = n & 7;
                int o = s * (KK * NLEAF) + k * NLEAF + leaf;
                loffA[k * 16 + n] = (idx_c[o] * (WR * WC) + idx_h[o] * WC + idx_w[o]) * 8;
            }
        }
        return;
    }
    int t = blockIdx.x * blockDim.x + threadIdx.x;
    if (t >= KK * 15) return;
    int k = t / 15, node = t % 15;
    const float* wp; int n;
    if (node < 8)       { wp = w0; n = node; }
    else if (node < 12) { wp = w1; n = node - 8; }
    else if (node < 14) { wp = w2; n = node - 12; }
    else                { wp = w3; n = 0; }
    const float* l = wp + (n * KK + k) * 16;
    float m = l[0];
    #pragma unroll
    for (int g = 1; g < 16; ++g) m = fmaxf(m, l[g]);
    float p[16], s = 0.f;
    #pragma unroll
    for (int g = 0; g < 16; ++g) { p[g] = expf(l[g] - m); s += p[g]; }
    float inv = 1.f / s;
    float c0 = 0, c1 = 0, c2 = 0, c3 = 0;
    #pragma unroll
    for (int g = 0; g < 16; ++g) {
        float w = p[g] * inv;
        c0 = fmaf(w, d_C[g][0], c0);
        c1 = fmaf(w, d_C[g][1], c1);
        c2 = fmaf(w, d_C[g][2], c2);
        c3 = fmaf(w, d_C[g][3], c3);
    }
    float* o = coefA + (k * 60 + node * 4);
    o[0] = c0; o[1] = c1; o[2] = c2; o[3] = c3;
}

__device__ __forceinline__ f32x2 bc(float s) { return (f32x2){s, s}; }
__device__ __forceinline__ f32x2 gate2(const float* c, f32x2 a, f32x2 b) {
    return __builtin_elementwise_fma(b,
               __builtin_elementwise_fma(a, bc(c[3]), bc(c[2])),
               __builtin_elementwise_fma(a, bc(c[1]), bc(c[0])));
}

// blockIdx = kh*512 + bp*64 + tile; tile = th*4 + tw (th: 16 row-tiles, tw: 4 col-tiles).
// 4 waves x 8 k each; lane = pixel of the 4x16 tile; f32x2 = 2 batch images.
__global__ __launch_bounds__(256) void logic_conv_kernel(
    const float* __restrict__ x, const int* __restrict__ loffA,
    const float* __restrict__ coefA, float* __restrict__ out)
{
    __shared__ f32x2 xt[WPOS];

    int tid = threadIdx.x;
    int kh  = blockIdx.x >> 9;
    int rem = blockIdx.x & 511;
    int bp  = rem >> 6;
    int t   = rem & 63;
    int r0  = (t >> 2) * TH;
    int c0  = (t & 3) * TCW;

    const float* xb0 = x + (size_t)(2 * bp) * (CIN * HW * HW);
    const float* xb1 = xb0 + (CIN * HW * HW);

    // Stage interleaved padded 32x8x20 windows for both images.
    #pragma unroll
    for (int i = 0; i < 20; ++i) {
        int e  = tid + i * 256;
        int c  = e / (WR * WC);
        int r  = e - c * (WR * WC);
        int rr = r / WC;
        int cc = r - rr * WC;
        int ih = r0 + rr - PADDING, iw = c0 + cc - PADDING;
        f32x2 v = {0.f, 0.f};
        if ((unsigned)ih < HW && (unsigned)iw < HW) {
            int go = (c * HW + ih) * HW + iw;
            v.x = xb0[go];
            v.y = xb1[go];
        }
        xt[e] = v;
    }
    __syncthreads();

    int lane = tid & 63, wave = tid >> 6;
    int tr = lane >> 4, tc = lane & 15;
    int pxb   = (tr * WC + tc) * 8;            // per-lane LDS byte offset
    int pxout = (r0 + tr) * HW + (c0 + tc);    // per-lane output element offset
    float* outB0 = out + ((size_t)(2 * bp) << 18);
    float* outB1 = outB0 + (1 << 18);
    const char* xtb = (const char*)xt;

    int k0 = __builtin_amdgcn_readfirstlane((kh << 5) + (wave << 3));

    #pragma unroll 2
    for (int i = 0; i < 8; ++i) {
        int k = k0 + i;
        const int*   L = loffA + (k << 4);
        const float* C = coefA + k * 60;

        f32x2 g[16];
        #pragma unroll
        for (int n = 0; n < 16; ++n)
            g[n] = *(const f32x2*)(xtb + (L[n] + pxb));

        f32x2 v[8];
        #pragma unroll
        for (int n = 0; n < 8; ++n)
            v[n] = gate2(C + 4 * n, g[n], g[8 + n]);
        f32x2 u[4];
        #pragma unroll
        for (int n = 0; n < 4; ++n)
            u[n] = gate2(C + 32 + 4 * n, v[2 * n], v[2 * n + 1]);
        f32x2 t0 = gate2(C + 48, u[0], u[1]);
        f32x2 t1 = gate2(C + 52, u[2], u[3]);
        f32x2 r  = gate2(C + 56, t0, t1);

        int ko = (k << 12) + pxout;
        outB0[ko] = r.x;
        outB1[ko] = r.y;
    }
}

extern "C" void kernel_launch(void* const* d_in, const int* in_sizes, int n_in,
                              void* d_out, int out_size, void* d_ws, size_t ws_size,
                              hipStream_t stream) {
    const float* x     = (const float*)d_in[0];
    const int*   idx_h = (const int*)d_in[1];
    const int*   idx_w = (const int*)d_in[2];
    const int*   idx_c = (const int*)d_in[3];
    const float* w0    = (const float*)d_in[4];
    const float* w1    = (const float*)d_in[5];
    const float* w2    = (const float*)d_in[6];
    const float* w3    = (const float*)d_in[7];
    float* out   = (float*)d_out;

    float* coefA = (float*)d_ws;                      // 15,360 B
    int*   loffA = (int*)((char*)d_ws + 16384);       // 4,096 B

    hipLaunchKernelGGL(prep_kernel, dim3(5), dim3(256), 0, stream,
                       idx_h, idx_w, idx_c, w0, w1, w2, w3, coefA, loffA);
    // 2 k-halves * 8 batch-pairs * 64 tiles = 1024 blocks
    hipLaunchKernelGGL(logic_conv_kernel, dim3(1024), dim3(256), 0, stream,
                       x, loffA, coefA, out);
}